// Round 15
// baseline (188.597 us; speedup 1.0000x reference)
//
#include <hip/hip_runtime.h>

namespace {
constexpr int CC = 3, FF = 51;
constexpr int BB = 4;
constexpr int HOUT = 384, WOUT = 384;
constexpr int HIN = 434, WIN = 434;
constexpr int KY = 4;                 // vertical outputs per thread
constexpr int TILES = 3;              // sequential y-tiles per block
constexpr int LANES = 64;             // x-pixels per block
constexpr int NW = 4;                 // fx-split waves per block (13/13/13/12 taps)
constexpr int EXT = LANES + FF - 1;   // 114 valid f16 per channel strip
constexpr int LPAD = 128;             // strip pitch (f16), pow2 -> static indices
constexpr int NSTEP = FF + KY - 1;    // 54 input rows per tile
constexpr int NSG = CC * LPAD / LANES;   // 6 staged elems/lane
constexpr int NQW = 4;                // b64 LDS reads per (c, step)
constexpr int NPW = 8;                // f16 pairs per (t, step)
constexpr int SSTRIDE = NW * CC * LPAD;  // u16 elems per LDS buffer (1536)

using half2v = _Float16 __attribute__((ext_vector_type(2)));

// r4/r6-proven: __builtin_amdgcn_fdot2 emits v_dot2_f32_f16.
// (r5 lesson: hand-written VOP3P asm broke numerics — keep the builtin.)
__device__ __forceinline__ float fdot2f(half2v a, half2v b, float c) {
#if __has_builtin(__builtin_amdgcn_fdot2)
  return __builtin_amdgcn_fdot2(a, b, c, false);
#else
  return c + (float)a.x * (float)b.x + (float)a.y * (float)b.y;
#endif
}
}  // namespace

// r14 body + two changes:
//  (1) TILES=3 sequential y-tiles per block -> grid 768 = exactly 3 blocks/CU
//      (matches measured residency cap ~3.2 blocks/CU), one dispatch round,
//      no tail; prologue/epilogue and hp loads amortized/overlapped.
//  (2) In staging 2 steps ahead via svA/svB ping-pong (+6 VGPR): ~600 cyc
//      cover vs L2 latency ~225.
// No global_load_lds (r10-r12: DMA forces per-step vmcnt(0) drains).
__global__ __launch_bounds__(NW* LANES, 2) void sepconv_kernel(
    const float* __restrict__ In, const float* __restrict__ Ver,
    const float* __restrict__ Hor, float* __restrict__ Out) {
  const int lane = threadIdx.x;
  const int w = threadIdx.y;          // fx-quarter
  const int x0 = blockIdx.x * LANES;
  const int b = blockIdx.z;
  const int x = x0 + lane;
  const int fxBase = 13 * w;          // taps [fxBase, fxBase+ntaps)
  const int ntaps = (w < 3) ? 13 : 12;
  const int aw = (lane + fxBase) & 3;        // alignment class
  const int bw = lane + fxBase - aw;         // 4-f16-aligned strip base elem

  __shared__ __align__(16) unsigned short sIn[2][NW][CC][LPAD];
  __shared__ float sRed[NW - 1][CC][KY][LANES];
  unsigned short* const sflat = &sIn[0][0][0][0];

  const size_t HW = (size_t)HOUT * WOUT;

  float sA[NSG], sB[NSG];  // 2-step-ahead In staging (ping-pong)
  float vvA[KY], vvB[KY];  // 1-step-ahead Ver (ping-pong)

#define STAGE_LOAD(R, SV)                                                     \
  _Pragma("unroll") for (int k = 0; k < NSG; ++k) {                           \
    const int e = lane + (k & 1) * 64;                                        \
    const bool valid = ((k & 1) == 0) || (lane < EXT - LANES);                \
    SV[k] = valid ? inb[(size_t)((k >> 1) * HIN + (R)) * WIN + e] : 0.0f;     \
  }

#define STAGE_WRITE(BF, SV)                                                   \
  _Pragma("unroll") for (int k = 0; k < NSG; ++k) {                           \
    const int e = lane + (k & 1) * 64;                                        \
    sflat[(BF)*SSTRIDE + (w * CC + (k >> 1)) * LPAD + e] =                    \
        __builtin_bit_cast(unsigned short, (_Float16)SV[k]);                  \
  }

#define VV_G(R, V)                                                            \
  _Pragma("unroll") for (int t = 0; t < KY; ++t) {                            \
    const int u = (R)-t;                                                      \
    V[t] = (u >= 0 && u < FF)                                                 \
               ? verb[(size_t)u * HW + (size_t)t * WOUT]                      \
               : 0.0f;                                                        \
  }

#define COMPUTE(BF, V)                                                        \
  {                                                                           \
    _Pragma("unroll") for (int c = 0; c < CC; ++c) {                          \
      const unsigned short* rp = sflat + (BF)*SSTRIDE + (w * CC + c) * LPAD + bw; \
      float d[KY];                                                            \
      {                                                                       \
        const uint2 u2 = *reinterpret_cast<const uint2*>(rp);                 \
        const half2v p0 = __builtin_bit_cast(half2v, u2.x);                   \
        const half2v p1 = __builtin_bit_cast(half2v, u2.y);                   \
        _Pragma("unroll") for (int t = 0; t < KY; ++t) {                      \
          d[t] = fdot2f(p0, hp[t][0], 0.0f);                                  \
          d[t] = fdot2f(p1, hp[t][1], d[t]);                                  \
        }                                                                     \
      }                                                                       \
      _Pragma("unroll") for (int q = 1; q < NQW; ++q) {                       \
        const uint2 u2 = *reinterpret_cast<const uint2*>(rp + 4 * q);         \
        const half2v p0 = __builtin_bit_cast(half2v, u2.x);                   \
        const half2v p1 = __builtin_bit_cast(half2v, u2.y);                   \
        _Pragma("unroll") for (int t = 0; t < KY; ++t) {                      \
          d[t] = fdot2f(p0, hp[t][2 * q], d[t]);                              \
          d[t] = fdot2f(p1, hp[t][2 * q + 1], d[t]);                          \
        }                                                                     \
      }                                                                       \
      _Pragma("unroll") for (int t = 0; t < KY; ++t)                          \
        acc[c][t] = __builtin_fmaf(d[t], V[t], acc[c][t]);                    \
    }                                                                         \
  }

#pragma unroll 1
  for (int ty = 0; ty < TILES; ++ty) {
    const int y0 = (blockIdx.y * TILES + ty) * KY;

    // ---- per-tile bases ----
    const float* inb = In + ((size_t)b * CC * HIN + y0) * WIN + x0;
    const float* verb = Ver + (size_t)b * FF * HW + (size_t)y0 * WOUT + x;

    // ---- per-pixel horizontal taps for this wave's fx range (OOB -> 0)
    half2v hp[KY][NPW];
    {
      const float* horx = Hor + (size_t)b * FF * HW + x;
#pragma unroll
      for (int t = 0; t < KY; ++t) {
        const float* hb = horx + (size_t)(y0 + t) * WOUT;
#pragma unroll
        for (int j = 0; j < NPW; ++j) {
          const int u0 = 2 * j - aw;
          const int u1 = u0 + 1;
          float f0 =
              (u0 >= 0 && u0 < ntaps) ? hb[(size_t)(fxBase + u0) * HW] : 0.0f;
          float f1 =
              (u1 >= 0 && u1 < ntaps) ? hb[(size_t)(fxBase + u1) * HW] : 0.0f;
          half2v p;
          p.x = (_Float16)f0;  // RTE
          p.y = (_Float16)f1;
          hp[t][j] = p;
        }
      }
    }

    float acc[CC][KY] = {};

    // ---- prologue: buf0=row0; svB=row1, svA=row2 in flight; vvA=step 0
    STAGE_LOAD(0, sA);
    STAGE_WRITE(0, sA);
    STAGE_LOAD(1, sB);
    STAGE_LOAD(2, sA);
    VV_G(0, vvA);

    // ---- main loop: 2 steps/iter; In 2 ahead, Ver 1 ahead ----
#pragma unroll 1
    for (int r = 0; r < NSTEP; r += 2) {
      const int rB = (r + 3 < NSTEP) ? r + 3 : NSTEP - 1;  // clamped prefetch
      const int rA = (r + 4 < NSTEP) ? r + 4 : NSTEP - 1;
      STAGE_WRITE(1, sB);      // row r+1 -> buf1 (loaded 1 full iter ago)
      STAGE_LOAD(rB, sB);      // In row r+3 (used in 1.5 iters)
      VV_G(r + 1, vvB);        // Ver step r+1
      COMPUTE(0, vvA);         // step r
      STAGE_WRITE(0, sA);      // row r+2 -> buf0 (loaded 1 iter ago)
      STAGE_LOAD(rA, sA);      // In row r+4
      VV_G(r + 2, vvA);        // Ver step r+2 (r=52: guards -> zeros, unused)
      COMPUTE(1, vvB);         // step r+1
    }

    // ---- cross-wave fx reduction (4-way), then store ----
    __syncthreads();  // protect previous tile's sRed reads (tile 0: free)
    if (w > 0) {
#pragma unroll
      for (int c = 0; c < CC; ++c)
#pragma unroll
        for (int t = 0; t < KY; ++t) sRed[w - 1][c][t][lane] = acc[c][t];
    }
    __syncthreads();
    if (w == 0) {
      float* outb = Out + (size_t)b * CC * HW + (size_t)y0 * WOUT + x0 + lane;
#pragma unroll
      for (int c = 0; c < CC; ++c)
#pragma unroll
        for (int t = 0; t < KY; ++t)
          outb[(size_t)c * HW + (size_t)t * WOUT] =
              acc[c][t] + sRed[0][c][t][lane] + sRed[1][c][t][lane] +
              sRed[2][c][t][lane];
    }
  }
#undef STAGE_LOAD
#undef STAGE_WRITE
#undef VV_G
#undef COMPUTE
}

extern "C" void kernel_launch(void* const* d_in, const int* in_sizes, int n_in,
                              void* d_out, int out_size, void* d_ws, size_t ws_size,
                              hipStream_t stream) {
  const float* In = (const float*)d_in[0];
  const float* Ver = (const float*)d_in[1];
  const float* Hor = (const float*)d_in[2];
  float* Out = (float*)d_out;

  dim3 grid(WOUT / LANES, HOUT / (KY * TILES), BB);  // 6 x 32 x 4 = 768 blocks
  dim3 block(LANES, NW, 1);
  sepconv_kernel<<<grid, block, 0, stream>>>(In, Ver, Hor, Out);
}

// Round 16
// 181.598 us; speedup vs baseline: 1.0385x; 1.0385x over previous
//
#include <hip/hip_runtime.h>

namespace {
constexpr int CC = 3, FF = 51;
constexpr int BB = 4;
constexpr int HOUT = 384, WOUT = 384;
constexpr int HIN = 434, WIN = 434;
constexpr int WP = 448;               // padded In16 row (f16), 896 B, 8B-aligned
constexpr int KY = 4;                 // vertical outputs per thread
constexpr int LANES = 64;             // x-pixels per block
constexpr int NW = 4;                 // fx-split waves per block (13/13/13/12 taps)
constexpr int EXT = LANES + FF - 1;   // 114 valid f16 per channel strip
constexpr int LPAD = 128;             // fallback strip pitch
constexpr int NSTEP = FF + KY - 1;    // 54 input rows per tile (even)
constexpr int NSG = CC * LPAD / LANES;   // fallback staged elems/lane
constexpr int NQW = 4;                // chunks (4 f16) per (c, step)
constexpr int NPW = 8;                // f16 pairs per (t, step)
constexpr int SSTRIDE = NW * CC * LPAD;
constexpr size_t IN16_BYTES = (size_t)BB * CC * HIN * WP * 2;  // 4.67 MB

using half2v = _Float16 __attribute__((ext_vector_type(2)));

// r4/r6-proven: __builtin_amdgcn_fdot2 emits v_dot2_f32_f16.
// (r5 lesson: hand-written VOP3P asm broke numerics — keep the builtin.)
__device__ __forceinline__ float fdot2f(half2v a, half2v b, float c) {
#if __has_builtin(__builtin_amdgcn_fdot2)
  return __builtin_amdgcn_fdot2(a, b, c, false);
#else
  return c + (float)a.x * (float)b.x + (float)a.y * (float)b.y;
#endif
}
}  // namespace

// ---- pre-kernel: In f32 -> f16 (RTE) into row-padded (WP=448) d_ws ----
__global__ void cvt16_kernel(const float* __restrict__ in,
                             unsigned int* __restrict__ out, int n2) {
  int i = blockIdx.x * blockDim.x + threadIdx.x;
  const int stride = gridDim.x * blockDim.x;
  for (; i < n2; i += stride) {
    const int row = i / (WP / 2);
    const int p = i - row * (WP / 2);
    unsigned int v = 0;
    if (2 * p + 1 < WIN) {
      const float2 f = *reinterpret_cast<const float2*>(
          in + (size_t)row * WIN + 2 * p);
      const unsigned short lo = __builtin_bit_cast(unsigned short, (_Float16)f.x);
      const unsigned short hi = __builtin_bit_cast(unsigned short, (_Float16)f.y);
      v = ((unsigned int)hi << 16) | lo;
    }
    out[i] = v;
  }
}

// LDS-free main kernel: each lane holds its 16-f16 In window in registers
// (4x global_load_dwordx2 per channel, 8B-aligned via 4-aligned bw + padded
// rows). Deletes staging/cvt/ds_read/ds_write entirely (r15 analysis: that
// machinery was ~2/3 of VALU issue). Windows ping-pong 1 step ahead (wA/wB);
// Ver ping-pongs 1 ahead (r14-proven). LDS only for the fx-reduction.
__global__ __launch_bounds__(NW* LANES, 2) void sepconv_reg(
    const float* __restrict__ Ver, const float* __restrict__ Hor,
    float* __restrict__ Out, const unsigned short* __restrict__ In16) {
  const int lane = threadIdx.x;
  const int w = threadIdx.y;          // fx-quarter
  const int x0 = blockIdx.x * LANES;
  const int y0 = blockIdx.y * KY;
  const int b = blockIdx.z;
  const int x = x0 + lane;
  const int fxBase = 13 * w;          // taps [fxBase, fxBase+ntaps)
  const int ntaps = (w < 3) ? 13 : 12;
  const int aw = (lane + fxBase) & 3;  // alignment class
  const int bw = lane + fxBase - aw;   // 4-f16-aligned window base elem

  __shared__ float sRed[NW - 1][CC][KY][LANES];

  const size_t HW = (size_t)HOUT * WOUT;

  // ---- per-pixel horizontal taps (OOB -> 0), RTE-packed pairs ----
  half2v hp[KY][NPW];
  {
    const float* horx = Hor + (size_t)b * FF * HW + x;
#pragma unroll
    for (int t = 0; t < KY; ++t) {
      const float* hb = horx + (size_t)(y0 + t) * WOUT;
#pragma unroll
      for (int j = 0; j < NPW; ++j) {
        const int u0 = 2 * j - aw;
        const int u1 = u0 + 1;
        float f0 = (u0 >= 0 && u0 < ntaps) ? hb[(size_t)(fxBase + u0) * HW] : 0.0f;
        float f1 = (u1 >= 0 && u1 < ntaps) ? hb[(size_t)(fxBase + u1) * HW] : 0.0f;
        half2v p;
        p.x = (_Float16)f0;  // RTE
        p.y = (_Float16)f1;
        hp[t][j] = p;
      }
    }
  }

  // per-channel In16 window pointers (8B-aligned: (x0+bw)*2 and 896B rows)
  const unsigned short* inw[CC];
#pragma unroll
  for (int c = 0; c < CC; ++c)
    inw[c] = In16 + (((size_t)b * CC + c) * HIN + y0) * WP + x0 + bw;

  const float* verb = Ver + (size_t)b * FF * HW + (size_t)y0 * WOUT + x;

  float acc[CC][KY] = {};
  uint2 wA[CC][NQW], wB[CC][NQW];  // ping-pong register windows (48 VGPRs)
  float vvA[KY], vvB[KY];          // ping-pong Ver sets

  // window load for step R (rows y0+R always valid; x-overrun hits row pad)
#define WLOAD(R, W)                                                           \
  _Pragma("unroll") for (int c = 0; c < CC; ++c) {                            \
    const unsigned short* pc = inw[c] + (size_t)(R)*WP;                       \
    _Pragma("unroll") for (int q = 0; q < NQW; ++q)                           \
      W[c][q] = *reinterpret_cast<const uint2*>(pc + 4 * q);                  \
  }

  // guarded Ver load for step R into set V
#define VV_G(R, V)                                                            \
  _Pragma("unroll") for (int t = 0; t < KY; ++t) {                            \
    const int u = (R)-t;                                                      \
    V[t] = (u >= 0 && u < FF)                                                 \
               ? verb[(size_t)u * HW + (size_t)t * WOUT]                      \
               : 0.0f;                                                        \
  }

#define COMPUTEW(W, V)                                                        \
  {                                                                           \
    _Pragma("unroll") for (int c = 0; c < CC; ++c) {                          \
      float d[KY];                                                            \
      {                                                                       \
        const half2v p0 = __builtin_bit_cast(half2v, W[c][0].x);              \
        const half2v p1 = __builtin_bit_cast(half2v, W[c][0].y);              \
        _Pragma("unroll") for (int t = 0; t < KY; ++t) {                      \
          d[t] = fdot2f(p0, hp[t][0], 0.0f);                                  \
          d[t] = fdot2f(p1, hp[t][1], d[t]);                                  \
        }                                                                     \
      }                                                                       \
      _Pragma("unroll") for (int q = 1; q < NQW; ++q) {                       \
        const half2v p0 = __builtin_bit_cast(half2v, W[c][q].x);              \
        const half2v p1 = __builtin_bit_cast(half2v, W[c][q].y);              \
        _Pragma("unroll") for (int t = 0; t < KY; ++t) {                      \
          d[t] = fdot2f(p0, hp[t][2 * q], d[t]);                              \
          d[t] = fdot2f(p1, hp[t][2 * q + 1], d[t]);                          \
        }                                                                     \
      }                                                                       \
      _Pragma("unroll") for (int t = 0; t < KY; ++t)                          \
        acc[c][t] = __builtin_fmaf(d[t], V[t], acc[c][t]);                    \
    }                                                                         \
  }

  // ---- prologue ----
  WLOAD(0, wA);
  VV_G(0, vvA);

  // ---- main loop (r14-proven shape; loads 1 step ahead, all reg-tracked)
#pragma unroll 1
  for (int r = 0; r < NSTEP; r += 2) {
    const bool more = (r + 2 < NSTEP);
    WLOAD(r + 1, wB);
    VV_G(r + 1, vvB);
    COMPUTEW(wA, vvA);          // step r
    if (more) {
      WLOAD(r + 2, wA);
      VV_G(r + 2, vvA);
    }
    COMPUTEW(wB, vvB);          // step r+1
  }

  // ---- cross-wave fx reduction (4-way), then store ----
  if (w > 0) {
#pragma unroll
    for (int c = 0; c < CC; ++c)
#pragma unroll
      for (int t = 0; t < KY; ++t) sRed[w - 1][c][t][lane] = acc[c][t];
  }
  __syncthreads();
  if (w == 0) {
    float* outb = Out + (size_t)b * CC * HW + (size_t)y0 * WOUT + x0 + lane;
#pragma unroll
    for (int c = 0; c < CC; ++c)
#pragma unroll
      for (int t = 0; t < KY; ++t)
        outb[(size_t)c * HW + (size_t)t * WOUT] =
            acc[c][t] + sRed[0][c][t][lane] + sRed[1][c][t][lane] +
            sRed[2][c][t][lane];
  }
#undef WLOAD
#undef VV_G
#undef COMPUTEW
}

// ---- fallback: r14 kernel verbatim (used only if ws too small) ----
__global__ __launch_bounds__(NW* LANES, 2) void sepconv_fb(
    const float* __restrict__ In, const float* __restrict__ Ver,
    const float* __restrict__ Hor, float* __restrict__ Out) {
  const int lane = threadIdx.x;
  const int w = threadIdx.y;
  const int x0 = blockIdx.x * LANES;
  const int y0 = blockIdx.y * KY;
  const int b = blockIdx.z;
  const int x = x0 + lane;
  const int fxBase = 13 * w;
  const int ntaps = (w < 3) ? 13 : 12;
  const int aw = (lane + fxBase) & 3;
  const int bw = lane + fxBase - aw;

  __shared__ __align__(16) unsigned short sIn[2][NW][CC][LPAD];
  __shared__ float sRed[NW - 1][CC][KY][LANES];
  unsigned short* const sflat = &sIn[0][0][0][0];

  const size_t HW = (size_t)HOUT * WOUT;

  half2v hp[KY][NPW];
  {
    const float* horx = Hor + (size_t)b * FF * HW + x;
#pragma unroll
    for (int t = 0; t < KY; ++t) {
      const float* hb = horx + (size_t)(y0 + t) * WOUT;
#pragma unroll
      for (int j = 0; j < NPW; ++j) {
        const int u0 = 2 * j - aw;
        const int u1 = u0 + 1;
        float f0 = (u0 >= 0 && u0 < ntaps) ? hb[(size_t)(fxBase + u0) * HW] : 0.0f;
        float f1 = (u1 >= 0 && u1 < ntaps) ? hb[(size_t)(fxBase + u1) * HW] : 0.0f;
        half2v p;
        p.x = (_Float16)f0;
        p.y = (_Float16)f1;
        hp[t][j] = p;
      }
    }
  }

  const float* inb = In + ((size_t)b * CC * HIN + y0) * WIN + x0;
  const float* verb = Ver + (size_t)b * FF * HW + (size_t)y0 * WOUT + x;

  float acc[CC][KY] = {};
  float sv[NSG];
  float vvA[KY], vvB[KY];

#define STAGE_LOAD(R)                                                         \
  _Pragma("unroll") for (int k = 0; k < NSG; ++k) {                           \
    const int e = lane + (k & 1) * 64;                                        \
    const bool valid = ((k & 1) == 0) || (lane < EXT - LANES);                \
    sv[k] = valid ? inb[(size_t)((k >> 1) * HIN + (R)) * WIN + e] : 0.0f;     \
  }

#define STAGE_WRITE(BF)                                                       \
  _Pragma("unroll") for (int k = 0; k < NSG; ++k) {                           \
    const int e = lane + (k & 1) * 64;                                        \
    sflat[(BF)*SSTRIDE + (w * CC + (k >> 1)) * LPAD + e] =                    \
        __builtin_bit_cast(unsigned short, (_Float16)sv[k]);                  \
  }

#define VV_G(R, V)                                                            \
  _Pragma("unroll") for (int t = 0; t < KY; ++t) {                            \
    const int u = (R)-t;                                                      \
    V[t] = (u >= 0 && u < FF)                                                 \
               ? verb[(size_t)u * HW + (size_t)t * WOUT]                      \
               : 0.0f;                                                        \
  }

#define COMPUTE(BF, V)                                                        \
  {                                                                           \
    _Pragma("unroll") for (int c = 0; c < CC; ++c) {                          \
      const unsigned short* rp = sflat + (BF)*SSTRIDE + (w * CC + c) * LPAD + bw; \
      float d[KY];                                                            \
      {                                                                       \
        const uint2 u2 = *reinterpret_cast<const uint2*>(rp);                 \
        const half2v p0 = __builtin_bit_cast(half2v, u2.x);                   \
        const half2v p1 = __builtin_bit_cast(half2v, u2.y);                   \
        _Pragma("unroll") for (int t = 0; t < KY; ++t) {                      \
          d[t] = fdot2f(p0, hp[t][0], 0.0f);                                  \
          d[t] = fdot2f(p1, hp[t][1], d[t]);                                  \
        }                                                                     \
      }                                                                       \
      _Pragma("unroll") for (int q = 1; q < NQW; ++q) {                       \
        const uint2 u2 = *reinterpret_cast<const uint2*>(rp + 4 * q);         \
        const half2v p0 = __builtin_bit_cast(half2v, u2.x);                   \
        const half2v p1 = __builtin_bit_cast(half2v, u2.y);                   \
        _Pragma("unroll") for (int t = 0; t < KY; ++t) {                      \
          d[t] = fdot2f(p0, hp[t][2 * q], d[t]);                              \
          d[t] = fdot2f(p1, hp[t][2 * q + 1], d[t]);                          \
        }                                                                     \
      }                                                                       \
      _Pragma("unroll") for (int t = 0; t < KY; ++t)                          \
        acc[c][t] = __builtin_fmaf(d[t], V[t], acc[c][t]);                    \
    }                                                                         \
  }

  STAGE_LOAD(0);
  STAGE_WRITE(0);
  VV_G(0, vvA);
#pragma unroll 1
  for (int r = 0; r < NSTEP; r += 2) {
    const bool more = (r + 2 < NSTEP);
    STAGE_LOAD(r + 1);
    VV_G(r + 1, vvB);
    COMPUTE(0, vvA);
    STAGE_WRITE(1);
    if (more) {
      STAGE_LOAD(r + 2);
      VV_G(r + 2, vvA);
    }
    COMPUTE(1, vvB);
    if (more) { STAGE_WRITE(0); }
  }

  if (w > 0) {
#pragma unroll
    for (int c = 0; c < CC; ++c)
#pragma unroll
      for (int t = 0; t < KY; ++t) sRed[w - 1][c][t][lane] = acc[c][t];
  }
  __syncthreads();
  if (w == 0) {
    float* outb = Out + (size_t)b * CC * HW + (size_t)y0 * WOUT + x0 + lane;
#pragma unroll
    for (int c = 0; c < CC; ++c)
#pragma unroll
      for (int t = 0; t < KY; ++t)
        outb[(size_t)c * HW + (size_t)t * WOUT] =
            acc[c][t] + sRed[0][c][t][lane] + sRed[1][c][t][lane] +
            sRed[2][c][t][lane];
  }
#undef STAGE_LOAD
#undef STAGE_WRITE
#undef VV_G
#undef COMPUTE
}

extern "C" void kernel_launch(void* const* d_in, const int* in_sizes, int n_in,
                              void* d_out, int out_size, void* d_ws, size_t ws_size,
                              hipStream_t stream) {
  const float* In = (const float*)d_in[0];
  const float* Ver = (const float*)d_in[1];
  const float* Hor = (const float*)d_in[2];
  float* Out = (float*)d_out;

  dim3 grid(WOUT / LANES, HOUT / KY, BB);
  dim3 block(LANES, NW, 1);

  if (ws_size >= IN16_BYTES && d_ws != nullptr) {
    const int n2 = (int)((size_t)BB * CC * HIN * (WP / 2));
    cvt16_kernel<<<2048, 256, 0, stream>>>(In, (unsigned int*)d_ws, n2);
    sepconv_reg<<<grid, block, 0, stream>>>(Ver, Hor, Out,
                                            (const unsigned short*)d_ws);
  } else {
    sepconv_fb<<<grid, block, 0, stream>>>(In, Ver, Hor, Out);
  }
}